// Round 1
// baseline (444.385 us; speedup 1.0000x reference)
//
#include <hip/hip_runtime.h>
#include <hip/hip_bf16.h>

#define S_LEN 4096
#define DMODEL 512
#define NHEAD 8
#define HDIM 64

typedef __bf16 bf16x8 __attribute__((ext_vector_type(8)));
typedef float f32x4 __attribute__((ext_vector_type(4)));

// ---------------- projection (q/k): y[s][h][d] = sum_d' x[s][h][d'] W[d][d'] + b[d] ----------------
__global__ __launch_bounds__(256) void proj_kernel(const float* __restrict__ x,
                                                   const float* __restrict__ W,
                                                   const float* __restrict__ b,
                                                   __bf16* __restrict__ y) {
    __shared__ float Ws[64][65];
    int t = threadIdx.x;
    for (int i = t; i < 4096; i += 256) Ws[i >> 6][i & 63] = W[i];
    __syncthreads();
    int lane = t & 63;
    int gw = blockIdx.x * 4 + (t >> 6);          // gw = s*8 + h, 4 rows per block
    const float* xrow = x + (size_t)gw * 64;
    float xv = xrow[lane];
    float acc = b[lane];
#pragma unroll
    for (int i = 0; i < 64; ++i) acc += __shfl(xv, i) * Ws[lane][i];
    y[(size_t)gw * 64 + lane] = (__bf16)acc;
}

// ---------------- projection (v) with transpose: vt[h][d][s] ----------------
__global__ __launch_bounds__(256) void proj_v_kernel(const float* __restrict__ x,
                                                     const float* __restrict__ W,
                                                     const float* __restrict__ b,
                                                     __bf16* __restrict__ vt) {
    __shared__ float Ws[64][65];
    __shared__ float T[64][65];
    int h = blockIdx.x & 7, st = blockIdx.x >> 3;
    int s0 = st * 64;
    int t = threadIdx.x, lane = t & 63, w = t >> 6;
    for (int i = t; i < 4096; i += 256) Ws[i >> 6][i & 63] = W[i];
    __syncthreads();
    float bv = b[lane];
    for (int p = 0; p < 16; ++p) {
        int sl = w * 16 + p;
        float xv = x[((size_t)(s0 + sl) * 8 + h) * 64 + lane];
        float acc = bv;
#pragma unroll
        for (int i = 0; i < 64; ++i) acc += __shfl(xv, i) * Ws[lane][i];
        T[sl][lane] = acc;
    }
    __syncthreads();
    for (int p = 0; p < 16; ++p) {
        int d = p * 4 + w;
        vt[((size_t)h * 64 + d) * 4096 + s0 + lane] = (__bf16)T[lane][d];
    }
}

// ---------------- mask packing: pack[qi][w] bit ki = (mask[qi][ki] != 0) ----------------
__global__ __launch_bounds__(256) void maskpack_kernel(const int* __restrict__ mask,
                                                       unsigned int* __restrict__ pack) {
    int t = threadIdx.x, lane = t & 63;
    int gw = blockIdx.x * 4 + (t >> 6);          // wave id: qi*64 + seg
    int qi = gw >> 6, seg = gw & 63;
    int ki = seg * 64 + lane;
    unsigned long long bits = __ballot(mask[(size_t)qi * 4096 + ki] != 0);
    if (lane == 0) {
        pack[(size_t)qi * 128 + seg * 2]     = (unsigned int)bits;
        pack[(size_t)qi * 128 + seg * 2 + 1] = (unsigned int)(bits >> 32);
    }
}

// ---------------- f32 -> bf16 convert ----------------
__global__ __launch_bounds__(256) void cvt_kernel(const float* __restrict__ src,
                                                  __bf16* __restrict__ dst, int n) {
    int i = blockIdx.x * 256 + threadIdx.x;
    if (i < n) dst[i] = (__bf16)src[i];
}

// ---------------- flash attention ----------------
// block: h = bid&7 (one head per XCD for K/V L2 residency), qt = bid>>3
// 4 waves, wave handles 16 q rows; KV step = 64
__global__ __launch_bounds__(256) void attn_kernel(const __bf16* __restrict__ qb,
                                                   const __bf16* __restrict__ kb,
                                                   const __bf16* __restrict__ vt,
                                                   const unsigned int* __restrict__ mp,
                                                   __bf16* __restrict__ ao) {
    int bid = blockIdx.x;
    int h = bid & 7, qt = bid >> 3;
    int t = threadIdx.x, wave = t >> 6, lane = t & 63, lg = lane >> 4, lc = lane & 15;
    int q0 = qt * 64 + wave * 16;

    __shared__ __bf16 P[2][4][16 * 64];   // double-buffered, per-wave 16x64 tile, XOR-swizzled

    // Q fragments (A-layout: row = lane&15, k = (lane>>4)*8 + j)
    const __bf16* qrow = qb + ((size_t)(q0 + lc) * 8 + h) * 64 + lg * 8;
    bf16x8 qf0 = *(const bf16x8*)(qrow);
    bf16x8 qf1 = *(const bf16x8*)(qrow + 32);

    f32x4 o0 = {0,0,0,0}, o1 = {0,0,0,0}, o2 = {0,0,0,0}, o3 = {0,0,0,0};
    float m_[4] = {-3e38f, -3e38f, -3e38f, -3e38f};
    float l_[4] = {0.f, 0.f, 0.f, 0.f};

    const unsigned int* mprow[4];
#pragma unroll
    for (int r = 0; r < 4; ++r) mprow[r] = mp + (size_t)(q0 + lg * 4 + r) * 128;

    const __bf16* vbase = vt + (size_t)h * 64 * 4096;

    for (int kb_i = 0; kb_i < S_LEN; kb_i += 64) {
        int buf = (kb_i >> 6) & 1;
        // ---- QK^T: 4 tiles of 16q x 16k ----
        f32x4 sc[4];
#pragma unroll
        for (int kc = 0; kc < 4; ++kc) {
            const __bf16* kr = kb + ((size_t)(kb_i + kc * 16 + lc) * 8 + h) * 64 + lg * 8;
            bf16x8 kf0 = *(const bf16x8*)(kr);
            bf16x8 kf1 = *(const bf16x8*)(kr + 32);
            f32x4 z = {0,0,0,0};
            z = __builtin_amdgcn_mfma_f32_16x16x32_bf16(qf0, kf0, z, 0, 0, 0);
            z = __builtin_amdgcn_mfma_f32_16x16x32_bf16(qf1, kf1, z, 0, 0, 0);
            sc[kc] = z;
        }
        // ---- mask (before scale) + online softmax ----
        float pv[4][4];   // [kc][r]
        float tmax[4];
#pragma unroll
        for (int r = 0; r < 4; ++r) {
            unsigned int w0 = mprow[r][(kb_i >> 5)];
            unsigned int w1 = mprow[r][(kb_i >> 5) + 1];
            float vmax = -3e38f;
#pragma unroll
            for (int kc = 0; kc < 4; ++kc) {
                unsigned int wsel = (kc < 2) ? w0 : w1;
                int bitpos = (kc & 1) * 16 + lc;
                float val = ((wsel >> bitpos) & 1u) ? sc[kc][r] * 0.125f : -1.25e19f;
                pv[kc][r] = val;
                vmax = fmaxf(vmax, val);
            }
            tmax[r] = vmax;
        }
#pragma unroll
        for (int r = 0; r < 4; ++r) {
            float v = tmax[r];
            v = fmaxf(v, __shfl_xor(v, 1));
            v = fmaxf(v, __shfl_xor(v, 2));
            v = fmaxf(v, __shfl_xor(v, 4));
            v = fmaxf(v, __shfl_xor(v, 8));
            float mn = fmaxf(m_[r], v);
            float corr = __expf(m_[r] - mn);
            m_[r] = mn;
            float ps = 0.f;
#pragma unroll
            for (int kc = 0; kc < 4; ++kc) {
                float p = __expf(pv[kc][r] - mn);
                pv[kc][r] = p;
                ps += p;
            }
            ps += __shfl_xor(ps, 1);
            ps += __shfl_xor(ps, 2);
            ps += __shfl_xor(ps, 4);
            ps += __shfl_xor(ps, 8);
            l_[r] = l_[r] * corr + ps;
            o0[r] *= corr; o1[r] *= corr; o2[r] *= corr; o3[r] *= corr;
        }
        // ---- write P (bf16) to swizzled LDS ----
        char* pbase = (char*)&P[buf][wave][0];
#pragma unroll
        for (int kc = 0; kc < 4; ++kc)
#pragma unroll
            for (int r = 0; r < 4; ++r) {
                int row = lg * 4 + r, col = kc * 16 + lc;
                int byte = ((row * 64 + col) * 2) ^ ((row & 7) << 4);
                *(__bf16*)(pbase + byte) = (__bf16)pv[kc][r];
            }
        __syncthreads();
        // ---- PV: O += P * V ----
#pragma unroll
        for (int kk = 0; kk < 2; ++kk) {
            int byte = ((lc * 64 + kk * 32 + lg * 8) * 2) ^ ((lc & 7) << 4);
            bf16x8 pf = *(const bf16x8*)((const char*)&P[buf][wave][0] + byte);
            const __bf16* vb = vbase + kb_i + kk * 32 + lg * 8;
            o0 = __builtin_amdgcn_mfma_f32_16x16x32_bf16(pf, *(const bf16x8*)(vb + (size_t)(0 * 16 + lc) * 4096), o0, 0, 0, 0);
            o1 = __builtin_amdgcn_mfma_f32_16x16x32_bf16(pf, *(const bf16x8*)(vb + (size_t)(1 * 16 + lc) * 4096), o1, 0, 0, 0);
            o2 = __builtin_amdgcn_mfma_f32_16x16x32_bf16(pf, *(const bf16x8*)(vb + (size_t)(2 * 16 + lc) * 4096), o2, 0, 0, 0);
            o3 = __builtin_amdgcn_mfma_f32_16x16x32_bf16(pf, *(const bf16x8*)(vb + (size_t)(3 * 16 + lc) * 4096), o3, 0, 0, 0);
        }
    }
    // ---- epilogue: normalize, write bf16 [s][h*64+d] ----
#pragma unroll
    for (int r = 0; r < 4; ++r) {
        float inv = 1.0f / l_[r];
        int row = q0 + lg * 4 + r;
        __bf16* dst = ao + (size_t)row * 512 + h * 64;
        dst[0 * 16 + lc] = (__bf16)(o0[r] * inv);
        dst[1 * 16 + lc] = (__bf16)(o1[r] * inv);
        dst[2 * 16 + lc] = (__bf16)(o2[r] * inv);
        dst[3 * 16 + lc] = (__bf16)(o3[r] * inv);
    }
}

// ---------------- final FC: out[s][n] = sum_k ao[s][k] * Wfc[n][k] + bfc[n] ----------------
__global__ __launch_bounds__(256) void fc_kernel(const __bf16* __restrict__ ao,
                                                 const __bf16* __restrict__ Wb,
                                                 const float* __restrict__ bfc,
                                                 float* __restrict__ out) {
    int bid = blockIdx.x;
    int stile = bid >> 3, nt = bid & 7;
    int t = threadIdx.x, wave = t >> 6, lane = t & 63, lg = lane >> 4, lc = lane & 15;
    int s0 = stile * 64 + wave * 16;
    int n0 = nt * 64;
    f32x4 c0 = {0,0,0,0}, c1 = {0,0,0,0}, c2 = {0,0,0,0}, c3 = {0,0,0,0};
    for (int k0 = 0; k0 < 512; k0 += 32) {
        bf16x8 af = *(const bf16x8*)(ao + (size_t)(s0 + lc) * 512 + k0 + lg * 8);
        const __bf16* wb = Wb + k0 + lg * 8;
        c0 = __builtin_amdgcn_mfma_f32_16x16x32_bf16(af, *(const bf16x8*)(wb + (size_t)(n0 + 0 * 16 + lc) * 512), c0, 0, 0, 0);
        c1 = __builtin_amdgcn_mfma_f32_16x16x32_bf16(af, *(const bf16x8*)(wb + (size_t)(n0 + 1 * 16 + lc) * 512), c1, 0, 0, 0);
        c2 = __builtin_amdgcn_mfma_f32_16x16x32_bf16(af, *(const bf16x8*)(wb + (size_t)(n0 + 2 * 16 + lc) * 512), c2, 0, 0, 0);
        c3 = __builtin_amdgcn_mfma_f32_16x16x32_bf16(af, *(const bf16x8*)(wb + (size_t)(n0 + 3 * 16 + lc) * 512), c3, 0, 0, 0);
    }
#pragma unroll
    for (int r = 0; r < 4; ++r) {
        int row = s0 + lg * 4 + r;
        float* dst = out + (size_t)row * 512 + n0;
        dst[0 * 16 + lc] = c0[r] + bfc[n0 + 0 * 16 + lc];
        dst[1 * 16 + lc] = c1[r] + bfc[n0 + 1 * 16 + lc];
        dst[2 * 16 + lc] = c2[r] + bfc[n0 + 2 * 16 + lc];
        dst[3 * 16 + lc] = c3[r] + bfc[n0 + 3 * 16 + lc];
    }
}

extern "C" void kernel_launch(void* const* d_in, const int* in_sizes, int n_in,
                              void* d_out, int out_size, void* d_ws, size_t ws_size,
                              hipStream_t stream) {
    const float* query = (const float*)d_in[0];
    const float* key   = (const float*)d_in[1];
    const float* value = (const float*)d_in[2];
    const int*   mask  = (const int*)d_in[3];
    const float* Wq  = (const float*)d_in[4];
    const float* bq  = (const float*)d_in[5];
    const float* Wk  = (const float*)d_in[6];
    const float* bk  = (const float*)d_in[7];
    const float* Wv  = (const float*)d_in[8];
    const float* bv  = (const float*)d_in[9];
    const float* Wfc = (const float*)d_in[10];
    const float* bfc = (const float*)d_in[11];

    char* ws = (char*)d_ws;
    const size_t MB = 1024 * 1024;
    __bf16* q_bf   = (__bf16*)(ws + 0 * MB);      // 4 MB  [S][H][64]
    __bf16* k_bf   = (__bf16*)(ws + 4 * MB);      // 4 MB  [S][H][64]
    __bf16* vt     = (__bf16*)(ws + 8 * MB);      // 4 MB  [H][64][S]
    __bf16* ao     = (__bf16*)(ws + 12 * MB);     // 4 MB  [S][512]
    __bf16* wfc_bf = (__bf16*)(ws + 16 * MB);     // 0.5 MB
    unsigned int* mpack = (unsigned int*)(ws + 17 * MB);  // 2 MB [S][128]

    proj_kernel<<<8192, 256, 0, stream>>>(query, Wq, bq, q_bf);
    proj_kernel<<<8192, 256, 0, stream>>>(key, Wk, bk, k_bf);
    proj_v_kernel<<<512, 256, 0, stream>>>(value, Wv, bv, vt);
    maskpack_kernel<<<65536, 256, 0, stream>>>(mask, mpack);
    cvt_kernel<<<1024, 256, 0, stream>>>(Wfc, wfc_bf, 262144);
    attn_kernel<<<512, 256, 0, stream>>>(q_bf, k_bf, vt, mpack, ao);
    fc_kernel<<<512, 256, 0, stream>>>(ao, wfc_bf, bfc, (float*)d_out);
}